// Round 1
// baseline (506.064 us; speedup 1.0000x reference)
//
#include <hip/hip_runtime.h>
#include <cstdint>

typedef unsigned short u16;
typedef __attribute__((ext_vector_type(8))) short bf16x8;
typedef __attribute__((ext_vector_type(4))) float f32x4;

#define S_LEN 2048
#define DM    2048
#define NH    16
#define HDIM  128

__device__ __forceinline__ u16 f2bf(float f) {
  union { float f; unsigned u; } v; v.f = f;
  unsigned r = v.u + 0x7fffu + ((v.u >> 16) & 1u);
  return (u16)(r >> 16);
}
__device__ __forceinline__ float bf2f(u16 h) {
  union { unsigned u; float f; } v; v.u = ((unsigned)h) << 16;
  return v.f;
}

typedef __attribute__((address_space(3))) void lds_void_t;
typedef const __attribute__((address_space(1))) void gbl_void_t;
__device__ __forceinline__ void gload_lds16(const void* g, void* l) {
  __builtin_amdgcn_global_load_lds((gbl_void_t*)g, (lds_void_t*)l, 16, 0, 0);
}

// ---------------------------------------------------------------- convert
__global__ void cvt_k(const float* __restrict__ in, u16* __restrict__ out, int n) {
  int n4 = n >> 2;
  int stride = gridDim.x * blockDim.x;
  for (int i = blockIdx.x * blockDim.x + threadIdx.x; i < n4; i += stride) {
    float4 v = ((const float4*)in)[i];
    ushort4 o;
    o.x = f2bf(v.x); o.y = f2bf(v.y); o.z = f2bf(v.z); o.w = f2bf(v.w);
    ((ushort4*)out)[i] = o;
  }
}

// ---------------------------------------------------------------- GEMM  C = A (MxK) * B^T (B given as NxK row-major)
// m97-style 128x128 tile, BK=32, 4 waves (2x2), global_load_lds staging.
template <typename CT>
__global__ __launch_bounds__(256) void gemm_bt(const u16* __restrict__ A,
                                               const u16* __restrict__ Bm,
                                               CT* __restrict__ C,
                                               int M, int N, int K) {
  __shared__ u16 sA[128 * 32];
  __shared__ u16 sB[128 * 32];
  const int t = threadIdx.x;
  const int lane = t & 63, wid = t >> 6;
  const int r0 = lane & 15, kq = lane >> 4;
  const int wr = wid >> 1, wc = wid & 1;
  const long tile_m = (long)blockIdx.y * 128;
  const long tile_n = (long)blockIdx.x * 128;

  f32x4 acc[4][4];
#pragma unroll
  for (int i = 0; i < 4; ++i)
#pragma unroll
    for (int j = 0; j < 4; ++j)
      acc[i][j] = (f32x4){0.f, 0.f, 0.f, 0.f};

  const int rowA = t >> 2;          // 0..63
  const int colA = (t & 3) * 8;
  const u16* gA = A + (tile_m + rowA) * (long)K + colA;
  const u16* gB = Bm + (tile_n + rowA) * (long)K + colA;
  u16* lA = &sA[(wid * 16) * 32];   // wave-uniform LDS base (1 KB per wave per round)
  u16* lB = &sB[(wid * 16) * 32];

  for (int k0 = 0; k0 < K; k0 += 32) {
    __syncthreads();
    gload_lds16(gA + k0, lA);
    gload_lds16(gA + k0 + 64 * (long)K, lA + 64 * 32);
    gload_lds16(gB + k0, lB);
    gload_lds16(gB + k0 + 64 * (long)K, lB + 64 * 32);
    __syncthreads();
    bf16x8 af[4], bfr[4];
#pragma unroll
    for (int i = 0; i < 4; ++i)
      af[i] = *(const bf16x8*)&sA[(wr * 64 + i * 16 + r0) * 32 + kq * 8];
#pragma unroll
    for (int i = 0; i < 4; ++i)
      bfr[i] = *(const bf16x8*)&sB[(wc * 64 + i * 16 + r0) * 32 + kq * 8];
#pragma unroll
    for (int i = 0; i < 4; ++i)
#pragma unroll
      for (int j = 0; j < 4; ++j)
        acc[i][j] = __builtin_amdgcn_mfma_f32_16x16x32_bf16(af[i], bfr[j], acc[i][j], 0, 0, 0);
  }

#pragma unroll
  for (int i = 0; i < 4; ++i)
#pragma unroll
    for (int j = 0; j < 4; ++j)
#pragma unroll
      for (int r = 0; r < 4; ++r) {
        long grow = tile_m + wr * 64 + i * 16 + kq * 4 + r;
        long gcol = tile_n + wc * 64 + j * 16 + r0;
        float v = acc[i][j][r];
        if constexpr (sizeof(CT) == 2) C[grow * N + gcol] = (CT)f2bf(v);
        else                           C[grow * N + gcol] = v;
      }
}

// ---------------------------------------------------------------- RoPE + reshape to (B,H,S,HD)
// z = blockIdx.y : 0 -> q, 1 -> k
__global__ void rope_k(const u16* __restrict__ qkv, const float* __restrict__ cosT,
                       const float* __restrict__ sinT, u16* __restrict__ qt,
                       u16* __restrict__ kt) {
  int z = blockIdx.y;
  long idx = (long)blockIdx.x * blockDim.x + threadIdx.x;  // over 32*2048*64
  int hd2 = (int)(idx & 63);
  int s   = (int)((idx >> 6) & (S_LEN - 1));
  int bh  = (int)(idx >> 17);
  int b = bh >> 4, h = bh & 15;
  const u16* src = qkv + ((long)(b * S_LEN + s)) * 6144 + z * 2048 + h * HDIM + hd2 * 2;
  ushort2 p = *(const ushort2*)src;
  float e = bf2f(p.x), o = bf2f(p.y);
  float c = cosT[s * 64 + hd2], sn = sinT[s * 64 + hd2];
  float oe = e * c - o * sn;
  float oo = e * sn + o * c;
  u16* dst = (z ? kt : qt) + ((long)bh * S_LEN + s) * HDIM + hd2 * 2;
  ushort2 w; w.x = f2bf(oe); w.y = f2bf(oo);
  *(ushort2*)dst = w;
}

// ---------------------------------------------------------------- V transpose -> (B,H,HD,S)
__global__ void vtrans_k(const u16* __restrict__ qkv, u16* __restrict__ vt) {
  __shared__ u16 tile[64][65];
  int bh = blockIdx.z;
  int b = bh >> 4, h = bh & 15;
  int s0 = blockIdx.x * 64, d0 = blockIdx.y * 64;
  int tx = threadIdx.x, ty = threadIdx.y;  // (64,4)
#pragma unroll
  for (int i = 0; i < 64; i += 4) {
    int s = s0 + ty + i;
    tile[ty + i][tx] = qkv[((long)(b * S_LEN + s)) * 6144 + 4096 + h * HDIM + d0 + tx];
  }
  __syncthreads();
#pragma unroll
  for (int i = 0; i < 64; i += 4) {
    int d = d0 + ty + i;
    vt[((long)bh * HDIM + d) * S_LEN + s0 + tx] = tile[tx][ty + i];
  }
}

// ---------------------------------------------------------------- flash attention (causal)
// grid (S/128, B*H), 4 waves, each wave owns 32 q rows; KV step = 32.
__global__ __launch_bounds__(256) void flash_k(const u16* __restrict__ qt,
                                               const u16* __restrict__ kt,
                                               const u16* __restrict__ vt,
                                               u16* __restrict__ attn) {
  __shared__ u16 pbuf[4][2][16][32];
  const int t = threadIdx.x, lane = t & 63, wid = t >> 6;
  const int r0 = lane & 15, kq = lane >> 4;
  const int bh = blockIdx.y, b = bh >> 4, h = bh & 15;
  const int q0 = blockIdx.x * 128 + wid * 32;

  const u16* qb = qt + ((long)bh * S_LEN + q0) * HDIM;
  const u16* kb = kt + (long)bh * S_LEN * HDIM;
  const u16* vb = vt + (long)bh * HDIM * S_LEN;

  bf16x8 aq[2][4];
#pragma unroll
  for (int rg = 0; rg < 2; ++rg)
#pragma unroll
    for (int kk = 0; kk < 4; ++kk)
      aq[rg][kk] = *(const bf16x8*)(qb + (rg * 16 + r0) * HDIM + kk * 32 + kq * 8);

  f32x4 o[2][8];
  float mrow[2][4], lrow[2][4];
#pragma unroll
  for (int rg = 0; rg < 2; ++rg) {
#pragma unroll
    for (int dt = 0; dt < 8; ++dt) o[rg][dt] = (f32x4){0.f, 0.f, 0.f, 0.f};
#pragma unroll
    for (int r = 0; r < 4; ++r) { mrow[rg][r] = -1e30f; lrow[rg][r] = 0.f; }
  }

  const float sc = 0.08838834764831845f;  // 1/sqrt(128)

  for (int kv0 = 0; kv0 <= q0; kv0 += 32) {
    const bool diag = (kv0 == q0);
    bf16x8 bk[2][4];
#pragma unroll
    for (int kc = 0; kc < 2; ++kc)
#pragma unroll
      for (int kk = 0; kk < 4; ++kk)
        bk[kc][kk] = *(const bf16x8*)(kb + ((long)(kv0 + kc * 16 + r0)) * HDIM + kk * 32 + kq * 8);

    f32x4 sacc[2][2];
#pragma unroll
    for (int rg = 0; rg < 2; ++rg)
#pragma unroll
      for (int kc = 0; kc < 2; ++kc) {
        sacc[rg][kc] = (f32x4){0.f, 0.f, 0.f, 0.f};
#pragma unroll
        for (int kk = 0; kk < 4; ++kk)
          sacc[rg][kc] = __builtin_amdgcn_mfma_f32_16x16x32_bf16(aq[rg][kk], bk[kc][kk], sacc[rg][kc], 0, 0, 0);
      }

    bf16x8 bv[8];
#pragma unroll
    for (int dt = 0; dt < 8; ++dt)
      bv[dt] = *(const bf16x8*)(vb + ((long)(dt * 16 + r0)) * S_LEN + kv0 + kq * 8);

#pragma unroll
    for (int rg = 0; rg < 2; ++rg) {
      float p0v[4], p1v[4], corr[4];
#pragma unroll
      for (int r = 0; r < 4; ++r) {
        float s0v = sacc[rg][0][r] * sc;
        float s1v = sacc[rg][1][r] * sc;
        if (diag) {
          int qrow = q0 + rg * 16 + kq * 4 + r;
          if (kv0 + r0 > qrow)       s0v = -1e30f;
          if (kv0 + 16 + r0 > qrow)  s1v = -1e30f;
        }
        float mx = fmaxf(s0v, s1v);
        mx = fmaxf(mx, __shfl_xor(mx, 1));
        mx = fmaxf(mx, __shfl_xor(mx, 2));
        mx = fmaxf(mx, __shfl_xor(mx, 4));
        mx = fmaxf(mx, __shfl_xor(mx, 8));
        float mnew = fmaxf(mrow[rg][r], mx);
        float co = __expf(mrow[rg][r] - mnew);
        mrow[rg][r] = mnew;
        float p0 = __expf(s0v - mnew);
        float p1 = __expf(s1v - mnew);
        float rs = p0 + p1;
        rs += __shfl_xor(rs, 1);
        rs += __shfl_xor(rs, 2);
        rs += __shfl_xor(rs, 4);
        rs += __shfl_xor(rs, 8);
        lrow[rg][r] = lrow[rg][r] * co + rs;
        corr[r] = co;
        p0v[r] = p0; p1v[r] = p1;
      }
#pragma unroll
      for (int dt = 0; dt < 8; ++dt)
#pragma unroll
        for (int r = 0; r < 4; ++r)
          o[rg][dt][r] *= corr[r];
#pragma unroll
      for (int r = 0; r < 4; ++r) {
        pbuf[wid][rg][kq * 4 + r][r0]      = f2bf(p0v[r]);
        pbuf[wid][rg][kq * 4 + r][16 + r0] = f2bf(p1v[r]);
      }
      bf16x8 pa = *(const bf16x8*)&pbuf[wid][rg][r0][kq * 8];
#pragma unroll
      for (int dt = 0; dt < 8; ++dt)
        o[rg][dt] = __builtin_amdgcn_mfma_f32_16x16x32_bf16(pa, bv[dt], o[rg][dt], 0, 0, 0);
    }
  }

#pragma unroll
  for (int rg = 0; rg < 2; ++rg) {
    float inv[4];
#pragma unroll
    for (int r = 0; r < 4; ++r) inv[r] = 1.0f / lrow[rg][r];
#pragma unroll
    for (int dt = 0; dt < 8; ++dt)
#pragma unroll
      for (int r = 0; r < 4; ++r) {
        int srow = q0 + rg * 16 + kq * 4 + r;
        attn[((long)(b * S_LEN + srow)) * DM + h * HDIM + dt * 16 + r0] =
            f2bf(o[rg][dt][r] * inv[r]);
      }
  }
}

// ---------------------------------------------------------------- launch
extern "C" void kernel_launch(void* const* d_in, const int* in_sizes, int n_in,
                              void* d_out, int out_size, void* d_ws, size_t ws_size,
                              hipStream_t stream) {
  (void)in_sizes; (void)n_in; (void)out_size; (void)ws_size;
  const float* x  = (const float*)d_in[0];
  const float* fc = (const float*)d_in[2];
  const float* fs = (const float*)d_in[3];
  const float* wq = (const float*)d_in[5];
  const float* wk = (const float*)d_in[6];
  const float* wv = (const float*)d_in[7];
  const float* wo = (const float*)d_in[8];
  float* out = (float*)d_out;

  // workspace layout (u16 elements): 151 MB total
  u16* xb   = (u16*)d_ws;            // 4096*2048
  u16* wqkv = xb + 8388608;          // 6144*2048
  u16* wob  = wqkv + 12582912;       // 2048*2048
  u16* qkv  = wob + 4194304;         // 4096*6144
  u16* qt   = qkv + 25165824;        // 32*2048*128
  u16* kt   = qt + 8388608;
  u16* vt   = kt + 8388608;
  u16* attn = qkv;                   // alias: qkv dead after rope/vtrans

  cvt_k<<<4096, 256, 0, stream>>>(x, xb, 8388608);
  cvt_k<<<2048, 256, 0, stream>>>(wq, wqkv, 4194304);
  cvt_k<<<2048, 256, 0, stream>>>(wk, wqkv + 4194304, 4194304);
  cvt_k<<<2048, 256, 0, stream>>>(wv, wqkv + 8388608, 4194304);
  cvt_k<<<2048, 256, 0, stream>>>(wo, wob, 4194304);

  gemm_bt<u16><<<dim3(48, 32), 256, 0, stream>>>(xb, wqkv, qkv, 4096, 6144, 2048);

  rope_k<<<dim3(16384, 2), 256, 0, stream>>>(qkv, fc, fs, qt, kt);
  vtrans_k<<<dim3(32, 2, 32), dim3(64, 4), 0, stream>>>(qkv, vt);

  flash_k<<<dim3(16, 32), 256, 0, stream>>>(qt, kt, vt, attn);

  gemm_bt<float><<<dim3(16, 32), 256, 0, stream>>>(attn, wob, out, 4096, 2048, 2048);
}